// Round 1
// 277.356 us; speedup vs baseline: 1.0334x; 1.0334x over previous
//
#include <hip/hip_runtime.h>
#include <cmath>

// x [B=4096][T=512][D=4], H=32, gates 4H=128 (PyTorch order i,f,g,o).
constexpr int T   = 512;
constexpr int D   = 4;
constexpr int H   = 32;
constexpr int BT  = 16;    // batch cols per block — ALL real
constexpr int BLK = 256;   // 4 waves: (layer, unit-half)

constexpr float LOG2E     = 1.44269504088896340736f;
constexpr float NEG2LOG2E = -2.88539008177792681472f;

// x staged as FULL zero-padded B-fragments (8 shorts/t). Col stride 4104
// shorts = 2052 dwords ≡ 4 (mod 32): the 16 per-iter broadcast b128 reads
// land 2-way per bank-quad (free). 16*4104*2B = 131.3 KB.
constexpr int XSTRIDE = 4104;
// h row stride 40 shorts = 20 dwords: b128 frag reads have bank-quad index
// (5*nl+q) mod 8 — exactly 2-way (nl vs nl+8) = free.
constexpr int HSTR = 40;

typedef short bf8 __attribute__((ext_vector_type(8)));  // 8 bf16 (4 VGPRs)
typedef short s4v __attribute__((ext_vector_type(4)));  // 4 bf16 (8B)
typedef float f4  __attribute__((ext_vector_type(4)));  // MFMA C/D
typedef float f2  __attribute__((ext_vector_type(2)));  // packed-f32 pair

// fp32 -> bf16 round-to-nearest-even (host-side-equivalent staging path)
static __device__ __forceinline__ short bf16_rtn(float v) {
    unsigned u = __float_as_uint(v);
    u += 0x7FFFu + ((u >> 16) & 1u);
    return (short)(u >> 16);
}

// R16: act path reworked for issue-rate —
//  - all non-trans act arithmetic packed as float2 r-pairs (v_pk_*_f32)
//  - one rcp per pair per site (R=rcp(a*b); 1/a=R*b, 1/b=R*a): 8->4 rcp/step
//  - h pack via v_cvt_pk_bf16_f32 (2 instrs vs ~12 of manual RTN math)
// Everything else (topology, staging, strides, MFMA chain) = R15.
__global__ __launch_bounds__(BLK, 1) void lstm_bf16p(
    const float* __restrict__ x,
    const float* __restrict__ W_ih0, const float* __restrict__ W_hh0,
    const float* __restrict__ b_ih0, const float* __restrict__ b_hh0,
    const float* __restrict__ W_ih1, const float* __restrict__ W_hh1,
    const float* __restrict__ b_ih1, const float* __restrict__ b_hh1,
    const float* __restrict__ W_out, const float* __restrict__ b_out,
    float* __restrict__ out)
{
    __shared__ __align__(16) short xbf[16 * XSTRIDE];   // 131.3 KB staged x frags
    __shared__ __align__(16) short h0b[2][16][HSTR];    // h, [buf][col][unit]
    __shared__ __align__(16) short h1b[2][16][HSTR];
    __shared__ __align__(16) float h1f[16][36];         // final h1 fp32 for the head

    const int tid   = threadIdx.x;
    const int w     = tid >> 6;
    const int lane  = tid & 63;
    const int q     = lane >> 4;       // quad
    const int nl    = lane & 15;       // batch col (all real)
    const int layer = w >> 1;          // 0: L1, 1: L2
    const int ug    = (w & 1) << 4;    // unit group offset 0 / 16
    const int b0    = blockIdx.x * BT;

    // ---- stage x -> zero-padded bf16 fragments ----
    for (int idx = tid; idx < 16 * T; idx += BLK) {
        const int col = idx & 15;
        const int t   = idx >> 4;
        float4 xv = *(const float4*)(x + ((size_t)(b0 + col) * T + t) * D);
        bf8 v = {0, 0, 0, 0, 0, 0, 0, 0};
        v[0] = bf16_rtn(xv.x); v[1] = bf16_rtn(xv.y);
        v[2] = bf16_rtn(xv.z); v[3] = bf16_rtn(xv.w);
        *(bf8*)&xbf[col * XSTRIDE + t * 8] = v;
    }
    // zero both h buffers
    for (int idx = tid; idx < 2 * 16 * HSTR; idx += BLK) {
        (&h0b[0][0][0])[idx] = 0;
        (&h1b[0][0][0])[idx] = 0;
    }

    // ---- weights: tile g = gate type. A-frag row = 32g + ug + nl, k = 8q+j.
    const float* W1 = layer ? W_ih1 : W_hh0;
    bf8 w1[4], w2[4];
    f4  bias[4];
    #pragma unroll
    for (int g = 0; g < 4; ++g) {
        const float sc = (g == 2) ? NEG2LOG2E : -LOG2E;
        const int row = 32 * g + ug + nl;
        #pragma unroll
        for (int j = 0; j < 8; ++j) {
            w1[g][j] = bf16_rtn(W1[row * H + 8 * q + j] * sc);
            float v2 = layer ? W_hh1[row * H + 8 * q + j]
                             : ((q == 0 && j < 4) ? W_ih0[row * D + j] : 0.0f);
            w2[g][j] = bf16_rtn(v2 * sc);
        }
        #pragma unroll
        for (int r = 0; r < 4; ++r) {
            const int gr = 32 * g + ug + 4 * q + r;
            bias[g][r] = sc * (layer ? (b_ih1[gr] + b_hh1[gr])
                                     : (b_ih0[gr] + b_hh0[gr]));
        }
    }

    // cell state, fp32, lane-local — carried as two packed pairs (r01, r23)
    f2 cA; cA.x = 0.0f; cA.y = 0.0f;
    f2 cB; cB.x = 0.0f; cB.y = 0.0f;

    const short* xcol = &xbf[nl * XSTRIDE];

    __syncthreads();

    // ---- packed activation for one r-pair ----
    // acc components pre-scaled: -log2e*z (i,f,o) / -2log2e*z (g).
    // c' = c/(1+ef) + (1-eg)/((1+ei)(1+eg));  h = (1-ec)/((1+eo)(1+ec)).
    // One rcp per pair per site via R=rcp(a*b) -> 1/a = R*b, 1/b = R*a.
    auto actpair = [&](f2& c2, float zi0, float zi1, float zf0, float zf1,
                       float zg0, float zg1, float zo0, float zo1,
                       unsigned& pkd, f2& hv) {
        f2 ei, ef, eg, eo, ec;
        ei.x = __builtin_amdgcn_exp2f(zi0); ei.y = __builtin_amdgcn_exp2f(zi1);
        ef.x = __builtin_amdgcn_exp2f(zf0); ef.y = __builtin_amdgcn_exp2f(zf1);
        eg.x = __builtin_amdgcn_exp2f(zg0); eg.y = __builtin_amdgcn_exp2f(zg1);
        eo.x = __builtin_amdgcn_exp2f(zo0); eo.y = __builtin_amdgcn_exp2f(zo1);
        f2 D1 = 1.0f + ef;
        f2 D2 = (1.0f + ei) * (1.0f + eg);
        f2 Dm = D1 * D2;
        float R = __builtin_amdgcn_rcpf(Dm.x * Dm.y);
        f2 rD; rD.x = R * Dm.y; rD.y = R * Dm.x;
        c2 = (c2 * D2 + (1.0f - eg) * D1) * rD;
        ec.x = __builtin_amdgcn_exp2f(c2.x * NEG2LOG2E);
        ec.y = __builtin_amdgcn_exp2f(c2.y * NEG2LOG2E);
        f2 Do = (1.0f + eo) * (1.0f + ec);
        float Ro = __builtin_amdgcn_rcpf(Do.x * Do.y);
        f2 ro; ro.x = Ro * Do.y; ro.y = Ro * Do.x;
        hv = (1.0f - ec) * ro;
        // dword = [bf16(hv.y) | bf16(hv.x)] — RNE pack, 1 instr
        asm("v_cvt_pk_bf16_f32 %0, %1, %2" : "=v"(pkd) : "v"(hv.x), "v"(hv.y));
    };

    // ---- one timestep; rb/wb are compile-time literals at each call site ----
    auto body = [&](const int i, const int rb, const int wb) {
        // issue all DS reads first
        bf8 b2;
        if (layer == 0) {   // x(i) fragment, pre-padded (i=T reads t=0, unused)
            b2 = *(const bf8*)&xcol[(i & (T - 1)) * 8];
        } else {            // h1(i-2)
            b2 = *(const bf8*)&h1b[rb][nl][8 * q];
        }
        bf8 b1 = *(const bf8*)&h0b[rb][nl][8 * q];              // h0(i-1)

        // ---- 8 MFMAs: 4 gate tiles x 2-chain (C starts at scaled bias) ----
        f4 acc[4];
        #pragma unroll
        for (int g = 0; g < 4; ++g) {
            f4 A = __builtin_amdgcn_mfma_f32_16x16x32_bf16(w2[g], b2, bias[g], 0, 0, 0);
            A    = __builtin_amdgcn_mfma_f32_16x16x32_bf16(w1[g], b1, A,       0, 0, 0);
            acc[g] = A;
        }

        // ---- lane-local state update: units ug+4q+r, col nl ----
        const bool act = layer ? (i >= 1) : (i < T);
        if (act) {
            unsigned pk0, pk1;
            f2 hvA, hvB;
            actpair(cA, acc[0][0], acc[0][1], acc[1][0], acc[1][1],
                        acc[2][0], acc[2][1], acc[3][0], acc[3][1], pk0, hvA);
            actpair(cB, acc[0][2], acc[0][3], acc[1][2], acc[1][3],
                        acc[2][2], acc[2][3], acc[3][2], acc[3][3], pk1, hvB);
            int2 hh; hh.x = (int)pk0; hh.y = (int)pk1;
            if (layer == 0) {
                *(int2*)&h0b[wb][nl][ug + 4 * q] = hh;
            } else {
                *(int2*)&h1b[wb][nl][ug + 4 * q] = hh;
                if (i == T) {   // h1(T-1), fp32, for the output head
                    float4 hw;
                    hw.x = hvA.x; hw.y = hvA.y; hw.z = hvB.x; hw.w = hvB.y;
                    *(float4*)&h1f[nl][ug + 4 * q] = hw;
                }
            }
        }
        __syncthreads();   // buffer wb becomes rb of the next step
    };

    #pragma unroll 1
    for (int i = 0; i < T; i += 2) {   // pairs (even: rb=0, odd: rb=1)
        body(i,     0, 1);
        body(i + 1, 1, 0);
    }
    body(T, 0, 1);                     // i = 512 (flush L2 step 511)

    // ---- output head: out[b0+n] = b_out + W_out . h1(T-1) ----
    if (tid < BT) {
        float acc = b_out[0];
        #pragma unroll
        for (int u = 0; u < H; ++u) acc = fmaf(W_out[u], h1f[tid][u], acc);
        out[b0 + tid] = acc;
    }
}

extern "C" void kernel_launch(void* const* d_in, const int* in_sizes, int n_in,
                              void* d_out, int out_size, void* d_ws, size_t ws_size,
                              hipStream_t stream) {
    const float* x     = (const float*)d_in[0];
    const float* W_ih0 = (const float*)d_in[1];
    const float* W_hh0 = (const float*)d_in[2];
    const float* b_ih0 = (const float*)d_in[3];
    const float* b_hh0 = (const float*)d_in[4];
    const float* W_ih1 = (const float*)d_in[5];
    const float* W_hh1 = (const float*)d_in[6];
    const float* b_ih1 = (const float*)d_in[7];
    const float* b_hh1 = (const float*)d_in[8];
    const float* W_out = (const float*)d_in[9];
    const float* b_out = (const float*)d_in[10];
    float* out = (float*)d_out;

    const int B = out_size;          // 4096
    lstm_bf16p<<<B / BT, BLK, 0, stream>>>(x, W_ih0, W_hh0, b_ih0, b_hh0,
                                           W_ih1, W_hh1, b_ih1, b_hh1,
                                           W_out, b_out, out);
}